// Round 6
// baseline (136.374 us; speedup 1.0000x reference)
//
#include <hip/hip_runtime.h>

// YOLOv2 loss, fused single-pass, non-temporal loads, ONE WAVE PER BLOCK.
// 2704 single-wave blocks over 256 CUs -> 10-11 blocks/CU (4% granularity tail)
// vs 676x4-wave blocks -> 2-3 blocks/CU (13.6% tail). Per-wave work is uniform:
// every anchor's score loop runs for ~every wave (P(any lane active) ~ 1).
// Layout: x[n, c, h, w], c = a*85 + k; strides: n=425*2704, c=2704, hw=1.
// One thread per cell (n,h,w); every fixed-c load is 256B contiguous per wave.

#define A_N 5
#define KPA 85
#define N_BATCH 64
#define HW 2704               // 52*52
#define CSTRIDE 2704
#define NSTRIDE (425 * 2704)
#define N_CELLS (N_BATCH * HW)   // 173056 = 2704 * 64 exactly
#define WPOS 5.0f
#define WNOOBJ 0.5f
#define EPSF 1e-8f

__device__ __forceinline__ float ldnt(const float* __restrict__ p) {
    return __builtin_nontemporal_load(p);
}

__global__ __launch_bounds__(64) void yolo_loss_kernel(
    const float* __restrict__ out, const float* __restrict__ gt,
    float* __restrict__ loss)
{
    const int idx = blockIdx.x * 64 + threadIdx.x;   // < N_CELLS exactly
    const int n  = idx / HW;
    const int hw = idx - n * HW;
    const int base = n * NSTRIDE + hw;

    float acc = 0.0f;

    // ---- gt confidences for all 5 anchors ----
    float gconf[A_N];
    bool anyObj = false, anyNoObj = false;
#pragma unroll
    for (int a = 0; a < A_N; ++a) {
        gconf[a] = ldnt(gt + base + (a * KPA + 4) * CSTRIDE);
        anyObj   |= (gconf[a] > 0.0f);
        anyNoObj |= (gconf[a] == 0.0f);
    }

    // ---- no-object confidence loss (g_conf exactly zero) ----
    if (anyNoObj) {
#pragma unroll
        for (int a = 0; a < A_N; ++a) {
            if (gconf[a] == 0.0f) {
                float oc = ldnt(out + base + (a * KPA + 4) * CSTRIDE);
                acc += WNOOBJ * oc * oc;
            }
        }
    }

    if (anyObj) {
        // ---- gt box = anchor 0's position ----
        float gb0 = ldnt(gt + base + 0 * CSTRIDE);
        float gb1 = ldnt(gt + base + 1 * CSTRIDE);
        float gb2 = ldnt(gt + base + 2 * CSTRIDE);
        float gb3 = ldnt(gt + base + 3 * CSTRIDE);
        const float areaB = fmaxf(gb2 - gb0, 0.0f) * fmaxf(gb3 - gb1, 0.0f);

        // ---- IoU of each predicted anchor box vs gt box; argmax (first max) ----
        float op[A_N][4];
        float iou[A_N];
#pragma unroll
        for (int a = 0; a < A_N; ++a) {
#pragma unroll
            for (int k = 0; k < 4; ++k)
                op[a][k] = ldnt(out + base + (a * KPA + k) * CSTRIDE);
            float w = fmaxf(fminf(op[a][2], gb2) - fmaxf(op[a][0], gb0), 0.0f);
            float h = fmaxf(fminf(op[a][3], gb3) - fmaxf(op[a][1], gb1), 0.0f);
            float inter = w * h;
            float areaA = fmaxf(op[a][2] - op[a][0], 0.0f) *
                          fmaxf(op[a][3] - op[a][1], 0.0f);
            iou[a] = inter / (areaA + areaB - inter + EPSF);
        }
        float best_iou = -1.0f;   // iou >= 0 always; strict > keeps first max
        int best = 0;
#pragma unroll
        for (int a = 0; a < A_N; ++a) {
            if (iou[a] > best_iou) { best_iou = iou[a]; best = a; }
        }

        // ---- responsible anchor: onehot(best) * has_obj ----
        if (gconf[best] > 0.0f) {
            float lp = 0.0f;
#pragma unroll
            for (int k = 0; k < 4; ++k) {
                float g = ldnt(gt + base + (best * KPA + k) * CSTRIDE);
                float d = op[best][k] - g;
                lp = fmaf(d, d, lp);
            }
            acc += WPOS * lp;
            float oc = ldnt(out + base + (best * KPA + 4) * CSTRIDE);
            float d = oc - best_iou;
            acc += d * d;
        }

        // ---- class-score loss for every anchor with an object ----
#pragma unroll
        for (int a = 0; a < A_N; ++a) {
            if (gconf[a] > 0.0f) {
                const int sb = base + (a * KPA + 5) * CSTRIDE;
                float s = 0.0f;
#pragma unroll 8
                for (int k = 0; k < 80; ++k) {
                    float d = ldnt(out + sb + k * CSTRIDE) -
                              ldnt(gt  + sb + k * CSTRIDE);
                    s = fmaf(d, d, s);
                }
                acc += s;
            }
        }
    }

    // ---- reduction: wave64 shuffle -> one atomic per (single-wave) block ----
#pragma unroll
    for (int off = 32; off > 0; off >>= 1)
        acc += __shfl_down(acc, off);

    if (threadIdx.x == 0) {
        atomicAdd(loss, acc * (1.0f / N_BATCH));
    }
}

extern "C" void kernel_launch(void* const* d_in, const int* in_sizes, int n_in,
                              void* d_out, int out_size, void* d_ws, size_t ws_size,
                              hipStream_t stream) {
    const float* out_p = (const float*)d_in[0];
    const float* gt_p  = (const float*)d_in[1];
    float* loss = (float*)d_out;

    // d_out is poisoned once and never re-poisoned between graph replays:
    // zero it ourselves every call (capture-safe async memset).
    hipMemsetAsync(loss, 0, sizeof(float), stream);

    const int threads = 64;
    const int blocks = N_CELLS / threads;   // 2704 exactly, one wave each
    yolo_loss_kernel<<<blocks, threads, 0, stream>>>(out_p, gt_p, loss);
}

// Round 7
// 106.452 us; speedup vs baseline: 1.2811x; 1.2811x over previous
//
#include <hip/hip_runtime.h>

// YOLOv2 loss, fused single-pass, non-temporal loads. (Round-5 kernel, reverted
// from the single-wave-block experiment: 64-thread blocks fragmented DRAM page
// locality and regressed 106->136 us. 4-wave blocks are the measured optimum.)
// Every input byte is consumed exactly once -> nt loads skip cache allocation
// churn on the 578 MB read stream (measured -4.2% vs plain loads).
// Layout: x[n, c, h, w], c = a*85 + k; strides: n=425*2704, c=2704, hw=1.
// One thread per cell (n,h,w); every fixed-c load is 256B contiguous per wave.

#define A_N 5
#define KPA 85
#define N_BATCH 64
#define HW 2704               // 52*52
#define CSTRIDE 2704
#define NSTRIDE (425 * 2704)
#define N_CELLS (N_BATCH * HW)   // 173056 = 676 * 256 exactly
#define WPOS 5.0f
#define WNOOBJ 0.5f
#define EPSF 1e-8f

__device__ __forceinline__ float ldnt(const float* __restrict__ p) {
    return __builtin_nontemporal_load(p);
}

__global__ __launch_bounds__(256) void yolo_loss_kernel(
    const float* __restrict__ out, const float* __restrict__ gt,
    float* __restrict__ loss)
{
    const int idx = blockIdx.x * blockDim.x + threadIdx.x;   // < N_CELLS exactly
    const int n  = idx / HW;
    const int hw = idx - n * HW;
    const int base = n * NSTRIDE + hw;

    float acc = 0.0f;

    // ---- gt confidences for all 5 anchors ----
    float gconf[A_N];
    bool anyObj = false, anyNoObj = false;
#pragma unroll
    for (int a = 0; a < A_N; ++a) {
        gconf[a] = ldnt(gt + base + (a * KPA + 4) * CSTRIDE);
        anyObj   |= (gconf[a] > 0.0f);
        anyNoObj |= (gconf[a] == 0.0f);
    }

    // ---- no-object confidence loss (g_conf exactly zero) ----
    if (anyNoObj) {
#pragma unroll
        for (int a = 0; a < A_N; ++a) {
            if (gconf[a] == 0.0f) {
                float oc = ldnt(out + base + (a * KPA + 4) * CSTRIDE);
                acc += WNOOBJ * oc * oc;
            }
        }
    }

    if (anyObj) {
        // ---- gt box = anchor 0's position ----
        float gb0 = ldnt(gt + base + 0 * CSTRIDE);
        float gb1 = ldnt(gt + base + 1 * CSTRIDE);
        float gb2 = ldnt(gt + base + 2 * CSTRIDE);
        float gb3 = ldnt(gt + base + 3 * CSTRIDE);
        const float areaB = fmaxf(gb2 - gb0, 0.0f) * fmaxf(gb3 - gb1, 0.0f);

        // ---- IoU of each predicted anchor box vs gt box; argmax (first max) ----
        float op[A_N][4];
        float iou[A_N];
#pragma unroll
        for (int a = 0; a < A_N; ++a) {
#pragma unroll
            for (int k = 0; k < 4; ++k)
                op[a][k] = ldnt(out + base + (a * KPA + k) * CSTRIDE);
            float w = fmaxf(fminf(op[a][2], gb2) - fmaxf(op[a][0], gb0), 0.0f);
            float h = fmaxf(fminf(op[a][3], gb3) - fmaxf(op[a][1], gb1), 0.0f);
            float inter = w * h;
            float areaA = fmaxf(op[a][2] - op[a][0], 0.0f) *
                          fmaxf(op[a][3] - op[a][1], 0.0f);
            iou[a] = inter / (areaA + areaB - inter + EPSF);
        }
        float best_iou = -1.0f;   // iou >= 0 always; strict > keeps first max
        int best = 0;
#pragma unroll
        for (int a = 0; a < A_N; ++a) {
            if (iou[a] > best_iou) { best_iou = iou[a]; best = a; }
        }

        // ---- responsible anchor: onehot(best) * has_obj ----
        if (gconf[best] > 0.0f) {
            float lp = 0.0f;
#pragma unroll
            for (int k = 0; k < 4; ++k) {
                float g = ldnt(gt + base + (best * KPA + k) * CSTRIDE);
                float d = op[best][k] - g;
                lp = fmaf(d, d, lp);
            }
            acc += WPOS * lp;
            float oc = ldnt(out + base + (best * KPA + 4) * CSTRIDE);
            float d = oc - best_iou;
            acc += d * d;
        }

        // ---- class-score loss for every anchor with an object ----
#pragma unroll
        for (int a = 0; a < A_N; ++a) {
            if (gconf[a] > 0.0f) {
                const int sb = base + (a * KPA + 5) * CSTRIDE;
                float s = 0.0f;
#pragma unroll 8
                for (int k = 0; k < 80; ++k) {
                    float d = ldnt(out + sb + k * CSTRIDE) -
                              ldnt(gt  + sb + k * CSTRIDE);
                    s = fmaf(d, d, s);
                }
                acc += s;
            }
        }
    }

    // ---- reduction: wave64 shuffle -> LDS -> one atomic per block ----
#pragma unroll
    for (int off = 32; off > 0; off >>= 1)
        acc += __shfl_down(acc, off);

    __shared__ float wsum[4];
    const int lane = threadIdx.x & 63;
    const int wid  = threadIdx.x >> 6;
    if (lane == 0) wsum[wid] = acc;
    __syncthreads();
    if (threadIdx.x == 0) {
        float s = (wsum[0] + wsum[1] + wsum[2] + wsum[3]) * (1.0f / N_BATCH);
        atomicAdd(loss, s);
    }
}

extern "C" void kernel_launch(void* const* d_in, const int* in_sizes, int n_in,
                              void* d_out, int out_size, void* d_ws, size_t ws_size,
                              hipStream_t stream) {
    const float* out_p = (const float*)d_in[0];
    const float* gt_p  = (const float*)d_in[1];
    float* loss = (float*)d_out;

    // d_out is poisoned once and never re-poisoned between graph replays:
    // zero it ourselves every call (capture-safe async memset).
    hipMemsetAsync(loss, 0, sizeof(float), stream);

    const int threads = 256;
    const int blocks = N_CELLS / threads;   // 676 exactly
    yolo_loss_kernel<<<blocks, threads, 0, stream>>>(out_p, gt_p, loss);
}